// Round 4
// baseline (218.195 us; speedup 1.0000x reference)
//
#include <hip/hip_runtime.h>
#include <hip/hip_bf16.h>
#include <math.h>

#define BATCH     256
#define DMODEL    2048
#define DSTATE    128
#define HEADDIM_  64
#define DINNER    4096
#define NHEADS_   64
#define CONVDIM   4352
#define DINPROJ   8512
#define EPS_      1e-5f

typedef __attribute__((ext_vector_type(8))) short short8;
typedef __attribute__((ext_vector_type(4))) short short4v;
typedef __attribute__((ext_vector_type(4))) float f32x4;

__device__ __forceinline__ short bfbits(float f) {
    __hip_bfloat16 h = __float2bfloat16(f);
    return *reinterpret_cast<short*>(&h);
}
__device__ __forceinline__ short8 cvt8(float4 a, float4 b) {
    short8 r;
    r[0] = bfbits(a.x); r[1] = bfbits(a.y); r[2] = bfbits(a.z); r[3] = bfbits(a.w);
    r[4] = bfbits(b.x); r[5] = bfbits(b.y); r[6] = bfbits(b.z); r[7] = bfbits(b.w);
    return r;
}
// XOR-swizzle for [rows][128B] bf16 LDS tiles (stride-128B col reads would be
// 16-way bank conflicts; row&7 into byte-bits 4..6 makes them 2-way = free).
__device__ __forceinline__ int swz(int row, int cb) {
    return row * 128 + (cb ^ ((row & 7) << 4));
}

// ---------- bf16 MFMA GEMM: C[256][N] = A[256][K] * W[N][K]^T ----------
// BM=256 (full M -> each W panel read ONCE), BN=32, BK=64.
// 256 thr = 4 waves stacked (wave w: rows w*64..w*64+63, all 32 cols),
// per wave m4 x n2 frags of 16x16x32. Double-buffered LDS (2x36KB), one
// barrier per K-step. grid=(N/32, 1, ksplit); block z -> C + z*256*ldc.
template<bool ABF>
__global__ __launch_bounds__(256, 2)
void gemm_mfma(const void* __restrict__ Av, const float* __restrict__ W,
               float* __restrict__ C, int lda, int ldb, int ldc, int kc) {
    const int bn0 = blockIdx.x * 32;
    const int k0  = blockIdx.z * kc;
    C += (size_t)blockIdx.z * 256 * ldc;
    const int t = threadIdx.x;
    const int lane = t & 63;
    const int w = t >> 6;
    const int fr = lane & 15, fg = lane >> 4;

    __shared__ __align__(16) char lds[2][36 * 1024];   // A 32K + B 4K per buf

    // staging: slot s -> row s>>3, 16B slot s&7 (8 bf16 elems)
    const float* apf[8]; const short* apb[8]; int ao[8];
    #pragma unroll
    for (int i = 0; i < 8; ++i) {
        int s = t + 256 * i, r = s >> 3, sl = s & 7;
        if (ABF) apb[i] = (const short*)Av + (size_t)r * lda + k0 + sl * 8;
        else     apf[i] = (const float*)Av + (size_t)r * lda + k0 + sl * 8;
        ao[i] = swz(r, sl * 16);
    }
    const int br = t >> 3, bsl = t & 7;
    const float* bp = W + (size_t)(bn0 + br) * ldb + k0 + bsl * 8;
    const int bo = 32 * 1024 + swz(br, bsl * 16);

    int aro[4], bro[2];
    #pragma unroll
    for (int m = 0; m < 4; ++m) aro[m] = swz(w * 64 + m * 16 + fr, fg * 16);
    #pragma unroll
    for (int n = 0; n < 2; ++n) bro[n] = 32 * 1024 + swz(n * 16 + fr, fg * 16);

    f32x4 acc[4][2] = {};
    float4 raf[8][2]; short8 rab[8];
    float4 rb0, rb1;

    #define LOADT(kt) { const int ko = (kt) << 6;                                        \
        _Pragma("unroll") for (int i = 0; i < 8; ++i) {                                  \
            if (ABF) rab[i] = *(const short8*)(apb[i] + ko);                             \
            else { raf[i][0] = *(const float4*)(apf[i] + ko);                            \
                   raf[i][1] = *(const float4*)(apf[i] + ko + 4); } }                    \
        rb0 = *(const float4*)(bp + ko); rb1 = *(const float4*)(bp + ko + 4); }
    #define STAGET(buf) {                                                                \
        _Pragma("unroll") for (int i = 0; i < 8; ++i)                                    \
            *(short8*)(lds[buf] + ao[i]) = ABF ? rab[i] : cvt8(raf[i][0], raf[i][1]);    \
        *(short8*)(lds[buf] + bo) = cvt8(rb0, rb1); }

    LOADT(0);
    STAGET(0);
    int cur = 0;
    const int nT = kc >> 6;
    for (int kt = 0; kt < nT; ++kt) {
        if (kt + 1 < nT) LOADT(kt + 1);
        __syncthreads();
        #pragma unroll
        for (int ks = 0; ks < 2; ++ks) {
            short8 af[4], bf[2];
            #pragma unroll
            for (int m = 0; m < 4; ++m) af[m] = *(short8*)(lds[cur] + (aro[m] ^ (ks << 6)));
            #pragma unroll
            for (int n = 0; n < 2; ++n) bf[n] = *(short8*)(lds[cur] + (bro[n] ^ (ks << 6)));
            #pragma unroll
            for (int m = 0; m < 4; ++m)
                #pragma unroll
                for (int n = 0; n < 2; ++n)
                    acc[m][n] = __builtin_amdgcn_mfma_f32_16x16x32_bf16(af[m], bf[n], acc[m][n], 0, 0, 0);
        }
        if (kt + 1 < nT) STAGET(cur ^ 1);
        cur ^= 1;
    }
    #pragma unroll
    for (int m = 0; m < 4; ++m)
        #pragma unroll
        for (int n = 0; n < 2; ++n) {
            const int row = w * 64 + m * 16 + fg * 4;
            const int col = bn0 + n * 16 + fr;
            #pragma unroll
            for (int j = 0; j < 4; ++j)
                C[(size_t)(row + j) * ldc + col] = acc[m][n][j];
        }
    #undef LOADT
    #undef STAGET
}

// sum 4 split-K partials (gemm2)
__global__ __launch_bounds__(256)
void reduce4(const float* __restrict__ part, float* __restrict__ out) {
    const int i = (blockIdx.x * 256 + threadIdx.x) * 4;
    float4 s = *(const float4*)(part + i);
    #pragma unroll
    for (int k = 1; k < 4; ++k) {
        float4 p = *(const float4*)(part + (size_t)k * BATCH * DMODEL + i);
        s.x += p.x; s.y += p.y; s.z += p.z; s.w += p.w;
    }
    *(float4*)(out + i) = s;
}

// ---------- fused conv1d+SiLU + per-(b,h) scalars (1024 thr = 16 waves) ----------
__global__ __launch_bounds__(1024)
void conv_scalars(const float* __restrict__ zx, const float* __restrict__ conv_state,
                  const float* __restrict__ conv_w, const float* __restrict__ conv_b,
                  const float* __restrict__ dt_bias, const float* __restrict__ A_log,
                  float* __restrict__ xbc, float* __restrict__ dtv,
                  float* __restrict__ dAv, float* __restrict__ BCv) {
    const int b = blockIdx.x, t = threadIdx.x;
    __shared__ float sBC[256];
    __shared__ float ws2[2];
    #pragma unroll
    for (int it = 0; it < 4; ++it) {
        int c = it * 1024 + t;
        float4 cs = *(const float4*)&conv_state[((size_t)b * CONVDIM + c) * 4];
        float4 w4 = *(const float4*)&conv_w[c * 4];
        float xin = zx[(size_t)b * DINPROJ + DINNER + c];
        float v = cs.y * w4.x + cs.z * w4.y + cs.w * w4.z + xin * w4.w + conv_b[c];
        xbc[(size_t)b * CONVDIM + c] = v / (1.f + expf(-v));
    }
    if (t < 256) {
        int c = 4096 + t;
        float4 cs = *(const float4*)&conv_state[((size_t)b * CONVDIM + c) * 4];
        float4 w4 = *(const float4*)&conv_w[c * 4];
        float xin = zx[(size_t)b * DINPROJ + DINNER + c];
        float v = cs.y * w4.x + cs.z * w4.y + cs.w * w4.z + xin * w4.w + conv_b[c];
        float sv = v / (1.f + expf(-v));
        xbc[(size_t)b * CONVDIM + c] = sv;
        sBC[t] = sv;
    }
    __syncthreads();
    if (t < 128) {
        float prod = sBC[t] * sBC[t + 128];
        #pragma unroll
        for (int m = 1; m < 64; m <<= 1) prod += __shfl_xor(prod, m);
        if ((t & 63) == 0) ws2[t >> 6] = prod;
    }
    __syncthreads();
    if (t == 0) BCv[b] = ws2[0] + ws2[1];
    if (t < NHEADS_) {
        float x = zx[(size_t)b * DINPROJ + DINNER + CONVDIM + t] + dt_bias[t];
        float dt = (x > 20.f) ? x : log1pf(expf(x));
        float dA = expf(dt * (-expf(A_log[t])));
        dtv[b * NHEADS_ + t] = dt;
        dAv[b * NHEADS_ + t] = dA;
    }
}

// ---------- SSM: y[b,h,p] = dA*(ssm[b,h,p,:]·C[b]) + x*(dt*(B·C)+D[h]) ----------
__global__ __launch_bounds__(256)
void ssm_kernel(const float* __restrict__ ssm, const float* __restrict__ xbc,
                const float* __restrict__ dtv, const float* __restrict__ dAv,
                const float* __restrict__ BCv, const float* __restrict__ Dp,
                float* __restrict__ y) {
    const int bh = blockIdx.x;
    const int b = bh >> 6, h = bh & 63;
    const int t = threadIdx.x;
    const float* S  = ssm + (size_t)bh * (HEADDIM_ * DSTATE);
    const float* Cp = xbc + (size_t)b * CONVDIM + DINNER + DSTATE;
    const float* xp = xbc + (size_t)b * CONVDIM + h * HEADDIM_;
    const float dA = dAv[bh];
    const float coef = dtv[bh] * BCv[b] + Dp[h];
    float4 c4 = *(const float4*)&Cp[(t & 31) * 4];
    #pragma unroll
    for (int it = 0; it < 8; ++it) {
        float4 s4 = *(const float4*)&S[it * 1024 + t * 4];
        float dot = s4.x * c4.x + s4.y * c4.y + s4.z * c4.z + s4.w * c4.w;
        #pragma unroll
        for (int m = 1; m < 32; m <<= 1) dot += __shfl_xor(dot, m);
        if ((t & 31) == 0) {
            int p = it * 8 + (t >> 5);
            y[(size_t)b * DINNER + h * HEADDIM_ + p] = dA * dot + xp[p] * coef;
        }
    }
}

// ---------- gate with silu(z) + RMSNorm -> bf16 (512 thr) ----------
__global__ __launch_bounds__(512)
void gate_norm(const float* __restrict__ y, const float* __restrict__ zx,
               const float* __restrict__ nw, short* __restrict__ yn) {
    const int b = blockIdx.x, t = threadIdx.x;
    float4 g[2];
    float ss = 0.f;
    #pragma unroll
    for (int it = 0; it < 2; ++it) {
        int i = it * 2048 + t * 4;
        float4 yv = *(const float4*)&y[(size_t)b * DINNER + i];
        float4 zv = *(const float4*)&zx[(size_t)b * DINPROJ + i];
        float4 gv;
        gv.x = yv.x * (zv.x / (1.f + expf(-zv.x)));
        gv.y = yv.y * (zv.y / (1.f + expf(-zv.y)));
        gv.z = yv.z * (zv.z / (1.f + expf(-zv.z)));
        gv.w = yv.w * (zv.w / (1.f + expf(-zv.w)));
        g[it] = gv;
        ss += gv.x * gv.x + gv.y * gv.y + gv.z * gv.z + gv.w * gv.w;
    }
    #pragma unroll
    for (int m = 1; m < 64; m <<= 1) ss += __shfl_xor(ss, m);
    __shared__ float wsum[8];
    if ((t & 63) == 0) wsum[t >> 6] = ss;
    __syncthreads();
    float tot = 0.f;
    #pragma unroll
    for (int k = 0; k < 8; ++k) tot += wsum[k];
    float sc = rsqrtf(tot * (1.f / DINNER) + EPS_);
    #pragma unroll
    for (int it = 0; it < 2; ++it) {
        int i = it * 2048 + t * 4;
        float4 wv = *(const float4*)&nw[i];
        float4 gv = g[it];
        short4v o;
        o[0] = bfbits(gv.x * sc * wv.x); o[1] = bfbits(gv.y * sc * wv.y);
        o[2] = bfbits(gv.z * sc * wv.z); o[3] = bfbits(gv.w * sc * wv.w);
        *(short4v*)&yn[(size_t)b * DINNER + i] = o;
    }
}

extern "C" void kernel_launch(void* const* d_in, const int* in_sizes, int n_in,
                              void* d_out, int out_size, void* d_ws, size_t ws_size,
                              hipStream_t stream) {
    const float* hid        = (const float*)d_in[0];
    const float* conv_state = (const float*)d_in[1];
    const float* ssm        = (const float*)d_in[2];
    const float* W_in       = (const float*)d_in[3];
    const float* conv_w     = (const float*)d_in[4];
    const float* conv_b     = (const float*)d_in[5];
    const float* dt_bias    = (const float*)d_in[6];
    const float* A_log      = (const float*)d_in[7];
    const float* Dp         = (const float*)d_in[8];
    const float* norm_w     = (const float*)d_in[9];
    const float* W_out      = (const float*)d_in[10];
    float* out = (float*)d_out;

    float* ws    = (float*)d_ws;
    float* zx    = ws;                                  // 256*8512 f32
    float* xbc   = zx  + (size_t)BATCH * DINPROJ;       // 256*4352 f32
    float* y     = xbc + (size_t)BATCH * CONVDIM;       // 256*4096 f32
    float* part  = y   + (size_t)BATCH * DINNER;        // 4*256*2048 f32
    float* dtv   = part + (size_t)4 * BATCH * DMODEL;   // 256*64
    float* dAv   = dtv + BATCH * NHEADS_;               // 256*64
    float* BCv   = dAv + BATCH * NHEADS_;               // 256
    short* yn_bf = (short*)(BCv + BATCH);               // 256*4096 bf16

    // 1) zxbcdt = h @ W_in^T  (N=8512, K=2048): 266 blocks, W_in read once
    gemm_mfma<false><<<dim3(DINPROJ / 32, 1, 1), 256, 0, stream>>>(
        hid, W_in, zx, DMODEL, DMODEL, DINPROJ, DMODEL);
    // 2) conv update + silu + dt/dA/(B·C)
    conv_scalars<<<dim3(BATCH), 1024, 0, stream>>>(
        zx, conv_state, conv_w, conv_b, dt_bias, A_log, xbc, dtv, dAv, BCv);
    // 3) SSM contraction (512 MiB ssm_state read)
    ssm_kernel<<<dim3(BATCH * NHEADS_), 256, 0, stream>>>(
        ssm, xbc, dtv, dAv, BCv, Dp, y);
    // 4) gate + RMSNorm -> bf16
    gate_norm<<<dim3(BATCH), 512, 0, stream>>>(y, zx, norm_w, yn_bf);
    // 5) out = yn @ W_out^T  (N=2048, K=4096): split-K x4 -> 256 balanced blocks
    gemm_mfma<true><<<dim3(DMODEL / 32, 1, 4), 256, 0, stream>>>(
        yn_bf, W_out, part, DINNER, DINNER, DMODEL, DINNER / 4);
    reduce4<<<dim3(BATCH * DMODEL / 1024), 256, 0, stream>>>(part, out);
}

// Round 5
// 181.410 us; speedup vs baseline: 1.2028x; 1.2028x over previous
//
#include <hip/hip_runtime.h>
#include <hip/hip_bf16.h>
#include <math.h>

#define BATCH     256
#define DMODEL    2048
#define DSTATE    128
#define HEADDIM_  64
#define DINNER    4096
#define NHEADS_   64
#define CONVDIM   4352
#define DINPROJ   8512
#define EPS_      1e-5f

typedef __attribute__((ext_vector_type(8))) short short8;
typedef __attribute__((ext_vector_type(4))) short short4v;
typedef __attribute__((ext_vector_type(4))) float f32x4;

__device__ __forceinline__ short bfbits(float f) {
    __hip_bfloat16 h = __float2bfloat16(f);
    return *reinterpret_cast<short*>(&h);
}
__device__ __forceinline__ short8 cvt8(float4 a, float4 b) {
    short8 r;
    r[0] = bfbits(a.x); r[1] = bfbits(a.y); r[2] = bfbits(a.z); r[3] = bfbits(a.w);
    r[4] = bfbits(b.x); r[5] = bfbits(b.y); r[6] = bfbits(b.z); r[7] = bfbits(b.w);
    return r;
}
// XOR-swizzle for [rows][128B] bf16 LDS tiles (kills 16-way conflicts on
// stride-128B fragment column reads; same map on write and read).
__device__ __forceinline__ int swz(int row, int cb) {
    return row * 128 + (cb ^ ((row & 7) << 4));
}

// ---------------- f32 -> bf16 pre-convert (hid, 512K elems) ----------------
__global__ __launch_bounds__(256)
void f2b(const float* __restrict__ in, short* __restrict__ o) {
    int i = (blockIdx.x * 256 + threadIdx.x) * 8;
    float4 a = *(const float4*)(in + i);
    float4 b = *(const float4*)(in + i + 4);
    *(short8*)(o + i) = cvt8(a, b);
}

// ---------- bf16 MFMA GEMM: C[256][N] = A[256][K](bf16) * W[N][K]^T(f32) ----------
// BM=256 fixed (full M). TH in {512 (BN=64, 8 waves 4x2), 256 (BN=32, 4 waves 4x1)}.
// Per wave 64x32 out = m4 x n2 frags 16x16x32, BK=64, dbuf LDS, 1 barrier/K-step.
// grid=(N/BN, 1, ksplit); block z adds into C + z*256*ldc (partials).
template<int TH, int BN>
__global__ __launch_bounds__(TH, 2)
void gemm_mfma(const short* __restrict__ A, const float* __restrict__ W,
               float* __restrict__ C, int lda, int ldb, int ldc, int kc) {
    constexpr int NW  = TH / 64;
    constexpr int WNC = BN / 32;           // n-waves
    constexpr int ASL = 2048 / TH;         // A 16B-slots per thread
    constexpr int BBYTES = BN * 128;       // B tile bytes (BN x 64 bf16)
    const int bn0 = blockIdx.x * BN;
    const int k0  = blockIdx.z * kc;
    C += (size_t)blockIdx.z * 256 * ldc;
    const int t = threadIdx.x;
    const int lane = t & 63;
    const int w = t >> 6;
    const int wm = w / WNC, wn = w % WNC;
    const int fr = lane & 15, fg = lane >> 4;

    __shared__ __align__(16) char lds[2][32768 + BBYTES];

    // A staging: slot s -> row s>>3, 16B slot s&7 (8 bf16)
    const short* apb[ASL]; int ao[ASL];
    #pragma unroll
    for (int i = 0; i < ASL; ++i) {
        int s = t + TH * i, r = s >> 3, sl = s & 7;
        apb[i] = A + (size_t)r * lda + k0 + sl * 8;
        ao[i] = swz(r, sl * 16);
    }
    // B staging: row t>>3 (TH == BN*8), slot t&7; f32 source, cvt on stage
    const int br = t >> 3, bsl = t & 7;
    const float* bp = W + (size_t)(bn0 + br) * ldb + k0 + bsl * 8;
    const int bo = 32768 + swz(br, bsl * 16);

    int aro[4], bro[2];
    #pragma unroll
    for (int m = 0; m < 4; ++m) aro[m] = swz(wm * 64 + m * 16 + fr, fg * 16);
    #pragma unroll
    for (int n = 0; n < 2; ++n) bro[n] = 32768 + swz(wn * 32 + n * 16 + fr, fg * 16);

    f32x4 acc[4][2] = {};
    short8 rab[ASL];
    float4 rb0, rb1;

    #define LOADT(kt) { const int ko = (kt) << 6;                                \
        _Pragma("unroll") for (int i = 0; i < ASL; ++i)                          \
            rab[i] = *(const short8*)(apb[i] + ko);                              \
        rb0 = *(const float4*)(bp + ko); rb1 = *(const float4*)(bp + ko + 4); }
    #define STAGET(buf) {                                                        \
        _Pragma("unroll") for (int i = 0; i < ASL; ++i)                          \
            *(short8*)(lds[buf] + ao[i]) = rab[i];                               \
        *(short8*)(lds[buf] + bo) = cvt8(rb0, rb1); }

    LOADT(0);
    STAGET(0);
    int cur = 0;
    const int nT = kc >> 6;
    for (int kt = 0; kt < nT; ++kt) {
        if (kt + 1 < nT) LOADT(kt + 1);
        __syncthreads();
        #pragma unroll
        for (int ks = 0; ks < 2; ++ks) {
            short8 af[4], bf[2];
            #pragma unroll
            for (int m = 0; m < 4; ++m) af[m] = *(short8*)(lds[cur] + (aro[m] ^ (ks << 6)));
            #pragma unroll
            for (int n = 0; n < 2; ++n) bf[n] = *(short8*)(lds[cur] + (bro[n] ^ (ks << 6)));
            #pragma unroll
            for (int m = 0; m < 4; ++m)
                #pragma unroll
                for (int n = 0; n < 2; ++n)
                    acc[m][n] = __builtin_amdgcn_mfma_f32_16x16x32_bf16(af[m], bf[n], acc[m][n], 0, 0, 0);
        }
        if (kt + 1 < nT) STAGET(cur ^ 1);
        cur ^= 1;
    }
    #pragma unroll
    for (int m = 0; m < 4; ++m)
        #pragma unroll
        for (int n = 0; n < 2; ++n) {
            const int row = wm * 64 + m * 16 + fg * 4;
            const int col = bn0 + wn * 32 + n * 16 + fr;
            #pragma unroll
            for (int j = 0; j < 4; ++j)
                C[(size_t)(row + j) * ldc + col] = acc[m][n][j];
        }
    #undef LOADT
    #undef STAGET
}

// sum 4 split-K partials (gemm2)
__global__ __launch_bounds__(256)
void reduce4(const float* __restrict__ part, float* __restrict__ out) {
    const int i = (blockIdx.x * 256 + threadIdx.x) * 4;
    float4 s = *(const float4*)(part + i);
    #pragma unroll
    for (int k = 1; k < 4; ++k) {
        float4 p = *(const float4*)(part + (size_t)k * BATCH * DMODEL + i);
        s.x += p.x; s.y += p.y; s.z += p.z; s.w += p.w;
    }
    *(float4*)(out + i) = s;
}

// ---------- fused middle: conv+silu -> scalars -> SSM -> gate+RMSNorm ----------
// One block per batch element b (256 blocks x 1024 thr = 1 block/CU).
// xBC and y never touch HBM; only ssm_state (2 MB/block) streams.
__global__ __launch_bounds__(1024)
void fused_mid(const float* __restrict__ zx, const float* __restrict__ conv_state,
               const float* __restrict__ conv_w, const float* __restrict__ conv_b,
               const float* __restrict__ dt_bias, const float* __restrict__ A_log,
               const float* __restrict__ ssm, const float* __restrict__ Dp,
               const float* __restrict__ nw, short* __restrict__ yn) {
    const int b = blockIdx.x, t = threadIdx.x;
    const int lane = t & 63, w = t >> 6;            // 16 waves
    __shared__ float sxbc[CONVDIM];                  // silu(conv(xBC)) : x|B|C
    __shared__ float sy[DINNER];                     // ssm output y
    __shared__ float sred[16];
    __shared__ float sdA[NHEADS_], scoef[NHEADS_];

    // ---- phase 1: conv + silu for all 4352 channels ----
    #pragma unroll
    for (int it = 0; it < 5; ++it) {
        int c = it * 1024 + t;
        if (c < CONVDIM) {
            float4 cs = *(const float4*)&conv_state[((size_t)b * CONVDIM + c) * 4];
            float4 w4 = *(const float4*)&conv_w[c * 4];
            float xin = zx[(size_t)b * DINPROJ + DINNER + c];
            float v = cs.y * w4.x + cs.z * w4.y + cs.w * w4.z + xin * w4.w + conv_b[c];
            sxbc[c] = v / (1.f + expf(-v));
        }
    }
    __syncthreads();

    // ---- phase 2: BC = B.C ; per-head dt, dA, coef ----
    if (t < 128) {
        float prod = sxbc[DINNER + t] * sxbc[DINNER + DSTATE + t];
        #pragma unroll
        for (int m = 1; m < 64; m <<= 1) prod += __shfl_xor(prod, m);
        if ((t & 63) == 0) sred[t >> 6] = prod;
    }
    __syncthreads();
    if (t < NHEADS_) {
        float BC = sred[0] + sred[1];
        float x = zx[(size_t)b * DINPROJ + DINNER + CONVDIM + t] + dt_bias[t];
        float dt = (x > 20.f) ? x : log1pf(expf(x));
        sdA[t] = expf(dt * (-expf(A_log[t])));
        scoef[t] = dt * BC + Dp[t];
    }
    __syncthreads();

    // ---- phase 3: y[h*64+p] = dA[h]*(S[b,h,p,:].C) + x[h*64+p]*coef[h] ----
    // wave w handles heads 4w..4w+3; lane = (pq = lane>>4) x (nl = lane&15).
    {
        const int pq = lane >> 4, nl = lane & 15;
        const float4 c4a = *(const float4*)&sxbc[DINNER + DSTATE + nl * 8];
        const float4 c4b = *(const float4*)&sxbc[DINNER + DSTATE + nl * 8 + 4];
        #pragma unroll
        for (int k = 0; k < 4; ++k) {
            const int h = w * 4 + k;
            const float* S = ssm + (((size_t)b * NHEADS_ + h) * HEADDIM_) * DSTATE;
            const float dA = sdA[h], coef = scoef[h];
            #pragma unroll 4
            for (int pp = 0; pp < 16; ++pp) {
                const int p = pp * 4 + pq;
                float4 sa = *(const float4*)&S[p * DSTATE + nl * 8];
                float4 sb = *(const float4*)&S[p * DSTATE + nl * 8 + 4];
                float dot = sa.x * c4a.x + sa.y * c4a.y + sa.z * c4a.z + sa.w * c4a.w
                          + sb.x * c4b.x + sb.y * c4b.y + sb.z * c4b.z + sb.w * c4b.w;
                #pragma unroll
                for (int m = 1; m < 16; m <<= 1) dot += __shfl_xor(dot, m);
                if (nl == 0)
                    sy[h * HEADDIM_ + p] = dA * dot + sxbc[h * HEADDIM_ + p] * coef;
            }
        }
    }
    __syncthreads();

    // ---- phase 4: gate with silu(z), RMSNorm, -> bf16 ----
    {
        const int i = t * 4;
        float4 yv = *(const float4*)&sy[i];
        float4 zv = *(const float4*)&zx[(size_t)b * DINPROJ + i];
        float4 g;
        g.x = yv.x * (zv.x / (1.f + expf(-zv.x)));
        g.y = yv.y * (zv.y / (1.f + expf(-zv.y)));
        g.z = yv.z * (zv.z / (1.f + expf(-zv.z)));
        g.w = yv.w * (zv.w / (1.f + expf(-zv.w)));
        float ss = g.x * g.x + g.y * g.y + g.z * g.z + g.w * g.w;
        #pragma unroll
        for (int m = 1; m < 64; m <<= 1) ss += __shfl_xor(ss, m);
        __syncthreads();                 // sred reuse: phase-2 readers done
        if (lane == 0) sred[w] = ss;
        __syncthreads();
        float tot = 0.f;
        #pragma unroll
        for (int k = 0; k < 16; ++k) tot += sred[k];
        const float sc = rsqrtf(tot * (1.f / DINNER) + EPS_);
        float4 w4 = *(const float4*)&nw[i];
        short4v o;
        o[0] = bfbits(g.x * sc * w4.x); o[1] = bfbits(g.y * sc * w4.y);
        o[2] = bfbits(g.z * sc * w4.z); o[3] = bfbits(g.w * sc * w4.w);
        *(short4v*)&yn[(size_t)b * DINNER + i] = o;
    }
}

extern "C" void kernel_launch(void* const* d_in, const int* in_sizes, int n_in,
                              void* d_out, int out_size, void* d_ws, size_t ws_size,
                              hipStream_t stream) {
    const float* hid        = (const float*)d_in[0];
    const float* conv_state = (const float*)d_in[1];
    const float* ssm        = (const float*)d_in[2];
    const float* W_in       = (const float*)d_in[3];
    const float* conv_w     = (const float*)d_in[4];
    const float* conv_b     = (const float*)d_in[5];
    const float* dt_bias    = (const float*)d_in[6];
    const float* A_log      = (const float*)d_in[7];
    const float* Dp         = (const float*)d_in[8];
    const float* norm_w     = (const float*)d_in[9];
    const float* W_out      = (const float*)d_in[10];
    float* out = (float*)d_out;

    float* ws    = (float*)d_ws;
    float* zx    = ws;                                  // 256*8512 f32
    float* part  = zx + (size_t)BATCH * DINPROJ;        // 4*256*2048 f32
    short* hidbf = (short*)(part + (size_t)4 * BATCH * DMODEL);  // 256*2048 bf16
    short* yn_bf = hidbf + (size_t)BATCH * DMODEL;      // 256*4096 bf16

    // 0) hid -> bf16 (A of gemm1 staged without per-block cvt)
    f2b<<<dim3(BATCH * DMODEL / 2048), 256, 0, stream>>>(hid, hidbf);
    // 1) zxbcdt = h @ W_in^T  (N=8512, K=2048): 133 blocks (<=256, no straggler),
    //    W_in read exactly once
    gemm_mfma<512, 64><<<dim3(DINPROJ / 64, 1, 1), 512, 0, stream>>>(
        hidbf, W_in, zx, DMODEL, DMODEL, DINPROJ, DMODEL);
    // 2) fused conv/scalars/SSM/gate-norm: 256 blocks = 1 per CU
    fused_mid<<<dim3(BATCH), 1024, 0, stream>>>(
        zx, conv_state, conv_w, conv_b, dt_bias, A_log, ssm, Dp, norm_w, yn_bf);
    // 3) out = yn @ W_out^T  (N=2048, K=4096): split-K x4 -> 256 balanced blocks
    gemm_mfma<256, 32><<<dim3(DMODEL / 32, 1, 4), 256, 0, stream>>>(
        yn_bf, W_out, part, DINNER, DINNER, DMODEL, DINNER / 4);
    reduce4<<<dim3(BATCH * DMODEL / 1024), 256, 0, stream>>>(part, out);
}